// Round 2
// baseline (17204.747 us; speedup 1.0000x reference)
//
#include <hip/hip_runtime.h>
#include <hip/hip_bf16.h>

// xLSTMStack: proj -> 4x( LN -> conv-mix -> bf16 MFMA GEMM (xg) -> cooperative GRU scan + residual )
// Workspace layout (~134.2 MiB):
//   [0,96M)     xg bf16 [B*L*3H]   (first 64 MiB aliased as ln fp32, consumed before xg written)
//   [96,128M)   mixbf bf16 [B*L*H] (GEMM A input + residual source for GRU)
//   [128,134M)  Wih bf16 [4*3H*H]
//   [134M,+128K) hst u64 [2][B][H] tagged (value,step) h-state
// d_out (fp32 [B,L,H]) doubles as the inter-layer h buffer.

#define B_   16
#define L_   2048
#define IN_  64
#define H_   512
#define H3_  1536
#define NL_  4

typedef unsigned short u16;
typedef unsigned long long u64;
typedef short bf16x8 __attribute__((ext_vector_type(8)));
typedef float f32x4 __attribute__((ext_vector_type(4)));

__device__ __forceinline__ u16 f2bf(float f) {
  unsigned u = __float_as_uint(f);
  u = u + 0x7fffu + ((u >> 16) & 1u);
  return (u16)(u >> 16);
}
__device__ __forceinline__ float bf2f(u16 v) {
  return __uint_as_float(((unsigned)v) << 16);
}
__device__ __forceinline__ float gelu_exact(float x) {
  return 0.5f * x * (1.f + erff(x * 0.70710678118654752440f));
}
__device__ __forceinline__ float sigmoidf_(float x) {
  return 1.f / (1.f + expf(-x));
}

// ---------------- init: zero tagged h-state ----------------
__global__ void k_init(u64* hst, int n) {
  int i = blockIdx.x * blockDim.x + threadIdx.x;
  if (i < n) hst[i] = 0ull;
}

// ---------------- fp32 -> bf16 convert ----------------
__global__ void k_cvt(const float* __restrict__ in, u16* __restrict__ out, int n) {
  int i = blockIdx.x * blockDim.x + threadIdx.x;
  int stride = gridDim.x * blockDim.x;
  for (; i < n; i += stride) out[i] = f2bf(in[i]);
}

// ---------------- input projection: h = x @ Wp.T + bp ----------------
// block 512 threads, 8 rows (m) per block
__global__ __launch_bounds__(512)
void k_proj(const float* __restrict__ x, const float* __restrict__ Wp,
            const float* __restrict__ bp, float* __restrict__ hb) {
  __shared__ float4 xs[128];
  const int tid = threadIdx.x;
  const size_t m0 = (size_t)blockIdx.x * 8;
  if (tid < 128) xs[tid] = ((const float4*)(x + m0 * IN_))[tid];
  __syncthreads();
  float4 wv[16];
  const float4* wp4 = (const float4*)(Wp + (size_t)tid * IN_);
#pragma unroll
  for (int i = 0; i < 16; ++i) wv[i] = wp4[i];
  float acc[8] = {0.f,0.f,0.f,0.f,0.f,0.f,0.f,0.f};
#pragma unroll
  for (int k = 0; k < 16; ++k) {
    float4 w4 = wv[k];
#pragma unroll
    for (int rr = 0; rr < 8; ++rr) {
      float4 xv = xs[rr * 16 + k];
      acc[rr] += w4.x * xv.x + w4.y * xv.y + w4.z * xv.z + w4.w * xv.w;
    }
  }
  float bpv = bp[tid];
#pragma unroll
  for (int rr = 0; rr < 8; ++rr) hb[(m0 + rr) * H_ + tid] = acc[rr] + bpv;
}

// ---------------- LayerNorm (one wave per row) ----------------
__global__ __launch_bounds__(256)
void k_ln(const float* __restrict__ hin, const float* __restrict__ g,
          const float* __restrict__ bta, float* __restrict__ lnout) {
  const int w = threadIdx.x >> 6, lane = threadIdx.x & 63;
  const size_t m = (size_t)blockIdx.x * 4 + w;
  const float4* src = (const float4*)(hin + m * H_);
  float4 a = src[lane * 2], c = src[lane * 2 + 1];
  float sm = a.x + a.y + a.z + a.w + c.x + c.y + c.z + c.w;
  float sq = a.x*a.x + a.y*a.y + a.z*a.z + a.w*a.w + c.x*c.x + c.y*c.y + c.z*c.z + c.w*c.w;
  sm += __shfl_xor(sm, 1);  sq += __shfl_xor(sq, 1);
  sm += __shfl_xor(sm, 2);  sq += __shfl_xor(sq, 2);
  sm += __shfl_xor(sm, 4);  sq += __shfl_xor(sq, 4);
  sm += __shfl_xor(sm, 8);  sq += __shfl_xor(sq, 8);
  sm += __shfl_xor(sm, 16); sq += __shfl_xor(sq, 16);
  sm += __shfl_xor(sm, 32); sq += __shfl_xor(sq, 32);
  float mu = sm * (1.f / 512.f);
  float var = sq * (1.f / 512.f) - mu * mu;
  float inv = 1.f / sqrtf(var + 1e-5f);
  const float4* g4 = (const float4*)g;
  const float4* b4 = (const float4*)bta;
  float4 ga = g4[lane * 2], gc = g4[lane * 2 + 1];
  float4 ba = b4[lane * 2], bc = b4[lane * 2 + 1];
  float4 oa, oc;
  oa.x = (a.x - mu) * inv * ga.x + ba.x;
  oa.y = (a.y - mu) * inv * ga.y + ba.y;
  oa.z = (a.z - mu) * inv * ga.z + ba.z;
  oa.w = (a.w - mu) * inv * ga.w + ba.w;
  oc.x = (c.x - mu) * inv * gc.x + bc.x;
  oc.y = (c.y - mu) * inv * gc.y + bc.y;
  oc.z = (c.z - mu) * inv * gc.z + bc.z;
  oc.w = (c.w - mu) * inv * gc.w + bc.w;
  float4* dst = (float4*)(lnout + m * H_);
  dst[lane * 2] = oa;
  dst[lane * 2 + 1] = oc;
}

// ---------------- fused conv(5,11,23)+BN+GELU+gate softmax+mix ----------------
// block 512 = one (b,t); thread = h
__global__ __launch_bounds__(512)
void k_mix(const float* __restrict__ ln,
           const float* __restrict__ w0, const float* __restrict__ cb0,
           const float* __restrict__ w1, const float* __restrict__ cb1,
           const float* __restrict__ w2, const float* __restrict__ cb2,
           const float* __restrict__ bng, const float* __restrict__ bnb,
           const float* __restrict__ gW, const float* __restrict__ gb,
           u16* __restrict__ mixbf) {
  const int h = threadIdx.x;
  const int bi = blockIdx.x >> 11;
  const int t = blockIdx.x & (L_ - 1);
  const size_t mrow = (size_t)blockIdx.x;
  float v[23];
#pragma unroll
  for (int d = 0; d < 23; ++d) {
    int tt = t + d - 11;
    v[d] = (tt >= 0 && tt < L_) ? ln[((size_t)bi * L_ + tt) * H_ + h] : 0.f;
  }
  float o0 = cb0[h], o1 = cb1[h], o2 = cb2[h];
#pragma unroll
  for (int d = 0; d < 5; ++d) o0 += v[9 + d] * w0[h * 5 + d];
#pragma unroll
  for (int d = 0; d < 11; ++d) o1 += v[6 + d] * w1[h * 11 + d];
#pragma unroll
  for (int d = 0; d < 23; ++d) o2 += v[d] * w2[h * 23 + d];
  const float bscale = 0.99999500003749968f;  // 1/sqrt(1+1e-5)
  o0 = o0 * (bng[0 * H_ + h] * bscale) + bnb[0 * H_ + h];
  o1 = o1 * (bng[1 * H_ + h] * bscale) + bnb[1 * H_ + h];
  o2 = o2 * (bng[2 * H_ + h] * bscale) + bnb[2 * H_ + h];
  o0 = gelu_exact(o0); o1 = gelu_exact(o1); o2 = gelu_exact(o2);
  float l0 = o0 * gW[0 * H3_ + h] + o1 * gW[0 * H3_ + H_ + h] + o2 * gW[0 * H3_ + 2 * H_ + h];
  float l1 = o0 * gW[1 * H3_ + h] + o1 * gW[1 * H3_ + H_ + h] + o2 * gW[1 * H3_ + 2 * H_ + h];
  float l2 = o0 * gW[2 * H3_ + h] + o1 * gW[2 * H3_ + H_ + h] + o2 * gW[2 * H3_ + 2 * H_ + h];
  l0 += __shfl_xor(l0, 1);  l1 += __shfl_xor(l1, 1);  l2 += __shfl_xor(l2, 1);
  l0 += __shfl_xor(l0, 2);  l1 += __shfl_xor(l1, 2);  l2 += __shfl_xor(l2, 2);
  l0 += __shfl_xor(l0, 4);  l1 += __shfl_xor(l1, 4);  l2 += __shfl_xor(l2, 4);
  l0 += __shfl_xor(l0, 8);  l1 += __shfl_xor(l1, 8);  l2 += __shfl_xor(l2, 8);
  l0 += __shfl_xor(l0, 16); l1 += __shfl_xor(l1, 16); l2 += __shfl_xor(l2, 16);
  l0 += __shfl_xor(l0, 32); l1 += __shfl_xor(l1, 32); l2 += __shfl_xor(l2, 32);
  __shared__ float red[8][3];
  const int w = h >> 6, lane = h & 63;
  if (lane == 0) { red[w][0] = l0; red[w][1] = l1; red[w][2] = l2; }
  __syncthreads();
  l0 = gb[0]; l1 = gb[1]; l2 = gb[2];
#pragma unroll
  for (int i = 0; i < 8; ++i) { l0 += red[i][0]; l1 += red[i][1]; l2 += red[i][2]; }
  float mx = fmaxf(l0, fmaxf(l1, l2));
  float e0 = expf(l0 - mx), e1 = expf(l1 - mx), e2 = expf(l2 - mx);
  float inv = 1.f / (e0 + e1 + e2);
  float out = (o0 * e0 + o1 * e1 + o2 * e2) * inv;
  mixbf[mrow * H_ + h] = f2bf(out);
}

// ---------------- bf16 MFMA GEMM: xg = mixbf @ WihT + bih ----------------
// A [M=32768, K=512] bf16, B [N=1536, K=512] bf16 (B^T layout), C bf16 [M,N]
// 128x128 tile, BK=32, 256 threads (2x2 waves, 64x64 each)
__global__ __launch_bounds__(256)
void k_gemm(const u16* __restrict__ A, const u16* __restrict__ Bm,
            const float* __restrict__ bias, u16* __restrict__ C) {
  __shared__ u16 As[128 * 32];
  __shared__ u16 Bs[128 * 32];
  const int tid = threadIdx.x;
  const int bm = blockIdx.x / 12, bn = blockIdx.x % 12;
  const int m0 = bm * 128, n0 = bn * 128;
  const int w = tid >> 6, lane = tid & 63;
  const int wr = w >> 1, wc = w & 1;
  const int q = lane >> 4, r = lane & 15;
  f32x4 acc[4][4] = {};
  const uint4* Ag = (const uint4*)(A + (size_t)m0 * H_);
  const uint4* Bg = (const uint4*)(Bm + (size_t)n0 * H_);
  uint4* As4 = (uint4*)As;
  uint4* Bs4 = (uint4*)Bs;
  for (int ko = 0; ko < 16; ++ko) {
    __syncthreads();
    // tile = 128 rows x 32 cols x 2B = 512 uint4; 256 threads -> 2 each
#pragma unroll
    for (int i = 0; i < 2; ++i) {
      int j = tid + 256 * i;
      As4[j] = Ag[(size_t)(j >> 2) * 64 + (j & 3) + ko * 4];
      Bs4[j] = Bg[(size_t)(j >> 2) * 64 + (j & 3) + ko * 4];
    }
    __syncthreads();
    bf16x8 av[4], bv[4];
#pragma unroll
    for (int m = 0; m < 4; ++m) av[m] = *(const bf16x8*)&As[(wr * 64 + m * 16 + r) * 32 + q * 8];
#pragma unroll
    for (int n = 0; n < 4; ++n) bv[n] = *(const bf16x8*)&Bs[(wc * 64 + n * 16 + r) * 32 + q * 8];
#pragma unroll
    for (int m = 0; m < 4; ++m)
#pragma unroll
      for (int n = 0; n < 4; ++n)
        acc[m][n] = __builtin_amdgcn_mfma_f32_16x16x32_bf16(av[m], bv[n], acc[m][n], 0, 0, 0);
  }
#pragma unroll
  for (int n = 0; n < 4; ++n) {
    int col = n0 + wc * 64 + n * 16 + r;
    float bv_ = bias[col];
#pragma unroll
    for (int m = 0; m < 4; ++m) {
      int row = m0 + wr * 64 + m * 16 + q * 4;
#pragma unroll
      for (int i = 0; i < 4; ++i) {
        float v = acc[m][n][i] + bv_;
        C[(size_t)(row + i) * H3_ + col] = f2bf(v);
      }
    }
  }
}

// ---------------- cooperative GRU scan ----------------
// 256 WGs x 512 threads. WG (b = wg>>4, s = wg&15) owns h-dims [32s,32s+32) -> 96 gate rows.
// Weights in registers: wave w, subgroup g16 -> rows rho = w*12+q*4+g16 (q=0..2), lane l16 -> k slice l16*32..+32.
// Cross-WG h exchange via tagged (value,step) u64 agent atomics, parity double-buffered.
__global__ __launch_bounds__(512, 2)
void k_gru(const float* __restrict__ Whh_l, const float* __restrict__ bhh_l,
           const u16* __restrict__ xg, const u16* __restrict__ mixbf,
           float* __restrict__ out_h, u64* hst, int tbase) {
  const int tid = threadIdx.x;
  const int wg = blockIdx.x;
  const int b = wg >> 4;
  const int s = wg & 15;
  const int w = tid >> 6;
  const int lane = tid & 63;
  const int g16 = lane >> 4;
  const int l16 = lane & 15;

  __shared__ float hg_s[96];
  __shared__ __align__(16) float h_s[2][576];  // 16 groups * 36-float padded rows

  float wr_[3][32];
  float bh_[3];
#pragma unroll
  for (int q = 0; q < 3; ++q) {
    const int rho = w * 12 + q * 4 + g16;
    const int gate = rho >> 5;
    const int jj = rho & 31;
    const int grow = gate * H_ + s * 32 + jj;
    const float4* wp = (const float4*)(Whh_l + (size_t)grow * H_ + l16 * 32);
#pragma unroll
    for (int c = 0; c < 8; ++c) {
      float4 v = wp[c];
      wr_[q][4 * c + 0] = v.x; wr_[q][4 * c + 1] = v.y;
      wr_[q][4 * c + 2] = v.z; wr_[q][4 * c + 3] = v.w;
    }
    bh_[q] = bhh_l[grow];
  }

  h_s[0][(tid >> 5) * 36 + (tid & 31)] = 0.f;  // h_{-1} = 0
  float hp = 0.f;                               // wave0 lanes<32: own h
  __syncthreads();

  const int PSTRIDE = B_ * H_;

  for (int t = 0; t < L_; ++t) {
    // prefetch gate inputs (wave0) so they land under the matvec
    u16 xr_u = 0, xz_u = 0, xn_u = 0, mx_u = 0;
    size_t orow = ((size_t)b * L_ + t) * H_ + s * 32 + lane;
    if (w == 0 && lane < 32) {
      size_t xb = ((size_t)b * L_ + t) * H3_ + s * 32 + lane;
      xr_u = xg[xb];
      xz_u = xg[xb + H_];
      xn_u = xg[xb + 2 * H_];
      mx_u = mixbf[orow];
    }
    // matvec partials: 3 rows per thread-group, 32 k each
    float p0 = 0.f, p1 = 0.f, p2 = 0.f;
    const float* hrow = &h_s[t & 1][l16 * 36];
#pragma unroll
    for (int c = 0; c < 8; ++c) {
      float4 hv = *(const float4*)(hrow + c * 4);
      p0 += wr_[0][4*c]*hv.x + wr_[0][4*c+1]*hv.y + wr_[0][4*c+2]*hv.z + wr_[0][4*c+3]*hv.w;
      p1 += wr_[1][4*c]*hv.x + wr_[1][4*c+1]*hv.y + wr_[1][4*c+2]*hv.z + wr_[1][4*c+3]*hv.w;
      p2 += wr_[2][4*c]*hv.x + wr_[2][4*c+1]*hv.y + wr_[2][4*c+2]*hv.z + wr_[2][4*c+3]*hv.w;
    }
    p0 += __shfl_xor(p0, 1); p1 += __shfl_xor(p1, 1); p2 += __shfl_xor(p2, 1);
    p0 += __shfl_xor(p0, 2); p1 += __shfl_xor(p1, 2); p2 += __shfl_xor(p2, 2);
    p0 += __shfl_xor(p0, 4); p1 += __shfl_xor(p1, 4); p2 += __shfl_xor(p2, 4);
    p0 += __shfl_xor(p0, 8); p1 += __shfl_xor(p1, 8); p2 += __shfl_xor(p2, 8);
    if (l16 == 0) {
      hg_s[w * 12 + 0 + g16] = p0 + bh_[0];
      hg_s[w * 12 + 4 + g16] = p1 + bh_[1];
      hg_s[w * 12 + 8 + g16] = p2 + bh_[2];
    }
    __syncthreads();

    if (w == 0 && lane < 32) {
      const int jj = lane;
      float hr = hg_s[jj], hz = hg_s[32 + jj], hn = hg_s[64 + jj];
      float r = sigmoidf_(bf2f(xr_u) + hr);
      float z = sigmoidf_(bf2f(xz_u) + hz);
      float n = tanhf(bf2f(xn_u) + r * hn);
      float hnew = (1.f - z) * n + z * hp;
      hp = hnew;
      out_h[orow] = bf2f(mx_u) + hnew;
      u64 pv = ((u64)(unsigned)(tbase + t + 1) << 32) | (u64)__float_as_uint(hnew);
      __hip_atomic_store(&hst[(size_t)((t + 1) & 1) * PSTRIDE + (size_t)b * H_ + s * 32 + jj],
                         pv, __ATOMIC_RELAXED, __HIP_MEMORY_SCOPE_AGENT);
    }

    if (t + 1 < L_) {
      const unsigned T = (unsigned)(tbase + t + 1);
      u64* sl = &hst[(size_t)((t + 1) & 1) * PSTRIDE + (size_t)b * H_ + tid];
      u64 v;
      do {
        v = __hip_atomic_load(sl, __ATOMIC_RELAXED, __HIP_MEMORY_SCOPE_AGENT);
      } while ((unsigned)(v >> 32) != T);
      h_s[(t + 1) & 1][(tid >> 5) * 36 + (tid & 31)] = __uint_as_float((unsigned)v);
    }
    __syncthreads();
  }
}

extern "C" void kernel_launch(void* const* d_in, const int* in_sizes, int n_in,
                              void* d_out, int out_size, void* d_ws, size_t ws_size,
                              hipStream_t stream) {
  (void)in_sizes; (void)n_in; (void)out_size; (void)ws_size;
  const float* x    = (const float*)d_in[0];
  const float* Wp   = (const float*)d_in[1];
  const float* bp   = (const float*)d_in[2];
  const float* ln_g = (const float*)d_in[3];
  const float* ln_b = (const float*)d_in[4];
  const float* cw0  = (const float*)d_in[5];
  const float* cb0  = (const float*)d_in[6];
  const float* cw1  = (const float*)d_in[7];
  const float* cb1  = (const float*)d_in[8];
  const float* cw2  = (const float*)d_in[9];
  const float* cb2  = (const float*)d_in[10];
  const float* bng  = (const float*)d_in[11];
  const float* bnb  = (const float*)d_in[12];
  const float* gW   = (const float*)d_in[13];
  const float* gb   = (const float*)d_in[14];
  const float* Wih  = (const float*)d_in[15];
  const float* Whh  = (const float*)d_in[16];
  const float* bih  = (const float*)d_in[17];
  const float* bhh  = (const float*)d_in[18];

  char* ws = (char*)d_ws;
  u16*   xg    = (u16*)(ws + 0);
  float* ln    = (float*)(ws + 0);  // alias: consumed (by k_mix) before k_gemm writes xg
  u16*   mixbf = (u16*)(ws + (size_t)96 * 1024 * 1024);
  u16*   wihbf = (u16*)(ws + (size_t)128 * 1024 * 1024);
  u64*   hst   = (u64*)(ws + (size_t)134 * 1024 * 1024);
  float* hbuf  = (float*)d_out;     // inter-layer h lives in d_out

  k_init<<<dim3(64), dim3(256), 0, stream>>>(hst, 2 * B_ * H_);
  k_cvt<<<dim3(3072), dim3(256), 0, stream>>>(Wih, wihbf, NL_ * H3_ * H_);
  k_proj<<<dim3(B_ * L_ / 8), dim3(512), 0, stream>>>(x, Wp, bp, hbuf);

  for (int l = 0; l < NL_; ++l) {
    k_ln<<<dim3(B_ * L_ / 4), dim3(256), 0, stream>>>(hbuf, ln_g + l * H_, ln_b + l * H_, ln);
    k_mix<<<dim3(B_ * L_), dim3(512), 0, stream>>>(ln,
        cw0 + l * H_ * 5,  cb0 + l * H_,
        cw1 + l * H_ * 11, cb1 + l * H_,
        cw2 + l * H_ * 23, cb2 + l * H_,
        bng + l * 3 * H_, bnb + l * 3 * H_,
        gW + l * 3 * H3_, gb + l * 3, mixbf);
    k_gemm<<<dim3((B_ * L_ / 128) * (H3_ / 128)), dim3(256), 0, stream>>>(
        mixbf, wihbf + (size_t)l * H3_ * H_, bih + l * H3_, xg);

    const float* whh_l = Whh + (size_t)l * H3_ * H_;
    const float* bhh_l = bhh + l * H3_;
    const u16* xg_c = xg;
    const u16* mix_c = mixbf;
    float* outp = hbuf;
    int tbase = l * L_;
    void* args[] = { (void*)&whh_l, (void*)&bhh_l, (void*)&xg_c, (void*)&mix_c,
                     (void*)&outp, (void*)&hst, (void*)&tbase };
    hipLaunchCooperativeKernel((void*)k_gru, dim3(B_ * 16), dim3(512), args, 0, stream);
  }
}